// Round 1
// baseline (569.323 us; speedup 1.0000x reference)
//
#include <hip/hip_runtime.h>

// Weird_Attention: key algebraic restructure (exact, reordering only):
//   plb_enhanced @ pv = glb_probs @ (plb_probs @ pv)
//   last = glb_probs @ gv + glb_probs @ (plb_probs@pv) = glb_probs @ (gv + plb_attn)
// => 6 proj GEMMs -> flash-attn(pq,pk,pv) -> v' = gv + plb_attn
//    -> flash-attn(gq,gk,v') -> dense GEMM.  232 GF -> 94 GF, no SxS matrices.

#define DEVI static __device__ __forceinline__

typedef __attribute__((ext_vector_type(4))) float f32x4;
typedef __attribute__((ext_vector_type(8))) __bf16 bf16x8;
typedef __attribute__((ext_vector_type(8))) short s16x8;
typedef __attribute__((ext_vector_type(4))) short s16x4;

constexpr int S = 1024, D = 1024, NH = 16, DH = 64, NB = 4;
constexpr int M = NB * S;   // 4096 rows for all big GEMMs
constexpr int KD = 1024;    // GEMM K
constexpr int ND = 1024;    // GEMM N

DEVI short f2bf(float f) {
  unsigned u = __builtin_bit_cast(unsigned, f);
  u += 0x7FFFu + ((u >> 16) & 1u);   // RNE
  return (short)(u >> 16);
}

DEVI f32x4 mfma_bf16(s16x8 a, s16x8 b, f32x4 c) {
  return __builtin_amdgcn_mfma_f32_16x16x32_bf16(
      __builtin_bit_cast(bf16x8, a), __builtin_bit_cast(bf16x8, b), c, 0, 0, 0);
}

DEVI void gll16(const void* g, void* l) {
  __builtin_amdgcn_global_load_lds(
      (const __attribute__((address_space(1))) unsigned*)g,
      (__attribute__((address_space(3))) unsigned*)l, 16, 0, 0);
}

// ---------------- casts ----------------
struct Ptrs3 { const float* p0; const float* p1; const float* p2; };
struct Ptrs7 { const float* p[7]; };

__global__ __launch_bounds__(256) void cast_inputs(Ptrs3 in, short* __restrict__ out) {
  int b = blockIdx.x;                       // 3 * 4096 blocks
  int which = b >> 12;
  const float* src = which == 0 ? in.p0 : (which == 1 ? in.p1 : in.p2);
  size_t local = ((size_t)(b & 4095) * 256 + threadIdx.x) * 4;
  f32x4 v = *(const f32x4*)(src + local);
  s16x4 o = { f2bf(v[0]), f2bf(v[1]), f2bf(v[2]), f2bf(v[3]) };
  *(s16x4*)(out + (size_t)which * ((size_t)M * KD) + local) = o;
}

__global__ __launch_bounds__(256) void cast_weights(Ptrs7 in, short* __restrict__ out) {
  int b = blockIdx.x;                       // 7 * 1024 blocks
  int which = b >> 10;
  size_t local = ((size_t)(b & 1023) * 256 + threadIdx.x) * 4;
  f32x4 v = *(const f32x4*)(in.p[which] + local);
  s16x4 o = { f2bf(v[0]), f2bf(v[1]), f2bf(v[2]), f2bf(v[3]) };
  *(s16x4*)(out + (size_t)which * 1048576 + local) = o;
}

// ---------------- GEMM: C[M,N] = A[M,K] @ Bw[N,K]^T + bias ----------------
// 128x128 tile, BK=32, 4 waves (2x2 of 64x64), mfma_f32_16x16x32_bf16.
// OUTMODE 0: bf16 [B,H,S,64]; 1: f32 [B,H,S,64]; 2: f32 [M,N] plain.
template <int OUTMODE>
__global__ __launch_bounds__(256) void gemm_bt(const short* __restrict__ A,
                                               const short* __restrict__ Bw,
                                               const float* __restrict__ bias,
                                               void* __restrict__ outp) {
  __shared__ short As[128 * 32];
  __shared__ short Bs[128 * 32];
  const int tid = threadIdx.x;
  const int lane = tid & 63, wave = tid >> 6;
  const int wr = wave >> 1, wc = wave & 1;
  const int l15 = lane & 15, lg = lane >> 4;
  const int rowBase = blockIdx.y * 128, colBase = blockIdx.x * 128;

  const int cr = tid >> 2, co = (tid & 3) * 8;   // staging: 16B chunks
  const short* gA0 = A + (size_t)(rowBase + cr) * KD + co;
  const short* gA1 = A + (size_t)(rowBase + 64 + cr) * KD + co;
  const short* gB0 = Bw + (size_t)(colBase + cr) * KD + co;
  const short* gB1 = Bw + (size_t)(colBase + 64 + cr) * KD + co;
  short* lA0 = As + tid * 8;
  short* lA1 = As + (tid + 256) * 8;
  short* lB0 = Bs + tid * 8;
  short* lB1 = Bs + (tid + 256) * 8;

  f32x4 acc[4][4] = {};
  for (int k0 = 0; k0 < KD; k0 += 32) {
    __syncthreads();                       // prev compute done before overwrite
    gll16(gA0 + k0, lA0);
    gll16(gA1 + k0, lA1);
    gll16(gB0 + k0, lB0);
    gll16(gB1 + k0, lB1);
    __syncthreads();                       // drains vmcnt before use
    s16x8 af[4], bf[4];
#pragma unroll
    for (int m = 0; m < 4; m++)
      af[m] = *(const s16x8*)(As + (wr * 64 + m * 16 + l15) * 32 + lg * 8);
#pragma unroll
    for (int n = 0; n < 4; n++)
      bf[n] = *(const s16x8*)(Bs + (wc * 64 + n * 16 + l15) * 32 + lg * 8);
#pragma unroll
    for (int m = 0; m < 4; m++)
#pragma unroll
      for (int n = 0; n < 4; n++)
        acc[m][n] = mfma_bf16(af[m], bf[n], acc[m][n]);
  }

  const int r0 = lg * 4;
#pragma unroll
  for (int m = 0; m < 4; m++)
#pragma unroll
    for (int n = 0; n < 4; n++)
#pragma unroll
      for (int i = 0; i < 4; i++) {
        int row = rowBase + wr * 64 + m * 16 + r0 + i;
        int col = colBase + wc * 64 + n * 16 + l15;
        float v = acc[m][n][i] + bias[col];
        if (OUTMODE == 2) {
          ((float*)outp)[(size_t)row * ND + col] = v;
        } else {
          size_t idx = (((size_t)(row >> 10) * NH + (col >> 6)) * S + (row & (S - 1))) * DH + (col & (DH - 1));
          if (OUTMODE == 1) ((float*)outp)[idx] = v;
          else              ((short*)outp)[idx] = f2bf(v);
        }
      }
}

// ---------------- transpose [BH,S,64] bf16 -> [BH,64,S] bf16 ----------------
__global__ __launch_bounds__(256) void transpose_bf16(const short* __restrict__ in,
                                                      short* __restrict__ out) {
  __shared__ short t[64 * 65];
  const int bh = blockIdx.y, s0 = blockIdx.x * 64;
  const int tid = threadIdx.x;
#pragma unroll
  for (int j = 0; j < 16; j++) {
    int e = j * 256 + tid;
    int s = e >> 6, d = e & 63;
    t[d * 65 + s] = in[((size_t)bh * S + s0 + s) * DH + d];
  }
  __syncthreads();
#pragma unroll
  for (int j = 0; j < 16; j++) {
    int e = j * 256 + tid;
    int d = e >> 6, s = e & 63;
    out[((size_t)bh * DH + d) * S + s0 + s] = t[d * 65 + s];
  }
}

// v' = bf16(gv + plb_attn), transposed to [BH,64,S]
__global__ __launch_bounds__(256) void vprime_t(const float* __restrict__ gv,
                                                const float* __restrict__ pa,
                                                short* __restrict__ out) {
  __shared__ short t[64 * 65];
  const int bh = blockIdx.y, s0 = blockIdx.x * 64;
  const int tid = threadIdx.x;
#pragma unroll
  for (int j = 0; j < 16; j++) {
    int e = j * 256 + tid;
    int s = e >> 6, d = e & 63;
    size_t idx = ((size_t)bh * S + s0 + s) * DH + d;
    t[d * 65 + s] = f2bf(gv[idx] + pa[idx]);
  }
  __syncthreads();
#pragma unroll
  for (int j = 0; j < 16; j++) {
    int e = j * 256 + tid;
    int d = e >> 6, s = e & 63;
    out[((size_t)bh * DH + d) * S + s0 + s] = t[d * 65 + s];
  }
}

// ---------------- flash attention ----------------
// Q,K: bf16 [BH,S,64]; Vt: bf16 [BH,64,S].  4 waves/block, 16 q-rows/wave,
// 64-key tiles, exact online softmax (scale 1/8).
// OUTMODE 0: f32 [BH,S,64]; 1: bf16 merged [B,S,D].
template <int OUTMODE>
__global__ __launch_bounds__(256) void attn64(const short* __restrict__ Q,
                                              const short* __restrict__ Km,
                                              const short* __restrict__ Vt,
                                              void* __restrict__ outp) {
  __shared__ short Pl[4 * 16 * 64];
  const int tid = threadIdx.x, lane = tid & 63, wave = tid >> 6;
  const int l15 = lane & 15, lg = lane >> 4;
  const int bh = blockIdx.y;
  const int q0 = blockIdx.x * 64 + wave * 16;

  const short* qp = Q + ((size_t)bh * S + q0 + l15) * DH + lg * 8;
  s16x8 qf0 = *(const s16x8*)qp;
  s16x8 qf1 = *(const s16x8*)(qp + 32);

  const short* kb = Km + (size_t)bh * S * DH;
  const short* vb = Vt + (size_t)bh * DH * S;
  short* myP = Pl + wave * 1024;   // private 16x64 bf16 P tile

  f32x4 acc[4] = {};
  float mrow[4], lrow[4];
#pragma unroll
  for (int i = 0; i < 4; i++) { mrow[i] = -1e30f; lrow[i] = 0.f; }

  for (int kt = 0; kt < S; kt += 64) {
    f32x4 sf[4] = {};
#pragma unroll
    for (int n = 0; n < 4; n++) {
      const short* kp = kb + (size_t)(kt + n * 16 + l15) * DH + lg * 8;
      s16x8 k0 = *(const s16x8*)kp;
      s16x8 k1 = *(const s16x8*)(kp + 32);
      sf[n] = mfma_bf16(qf0, k0, sf[n]);
      sf[n] = mfma_bf16(qf1, k1, sf[n]);
    }
    float tm[4];
#pragma unroll
    for (int i = 0; i < 4; i++) {
      sf[0][i] *= 0.125f; sf[1][i] *= 0.125f; sf[2][i] *= 0.125f; sf[3][i] *= 0.125f;
      tm[i] = fmaxf(fmaxf(sf[0][i], sf[1][i]), fmaxf(sf[2][i], sf[3][i]));
    }
#pragma unroll
    for (int off = 1; off < 16; off <<= 1)
#pragma unroll
      for (int i = 0; i < 4; i++) tm[i] = fmaxf(tm[i], __shfl_xor(tm[i], off));

    float al[4], ts[4];
#pragma unroll
    for (int i = 0; i < 4; i++) {
      float mn = fmaxf(mrow[i], tm[i]);
      al[i] = __expf(mrow[i] - mn);
      mrow[i] = mn;
    }
    f32x4 p[4];
#pragma unroll
    for (int n = 0; n < 4; n++)
#pragma unroll
      for (int i = 0; i < 4; i++) p[n][i] = __expf(sf[n][i] - mrow[i]);
#pragma unroll
    for (int i = 0; i < 4; i++) ts[i] = p[0][i] + p[1][i] + p[2][i] + p[3][i];
#pragma unroll
    for (int off = 1; off < 16; off <<= 1)
#pragma unroll
      for (int i = 0; i < 4; i++) ts[i] += __shfl_xor(ts[i], off);
#pragma unroll
    for (int i = 0; i < 4; i++) lrow[i] = lrow[i] * al[i] + ts[i];
#pragma unroll
    for (int n = 0; n < 4; n++)
#pragma unroll
      for (int i = 0; i < 4; i++) acc[n][i] *= al[i];

    // P (C-layout) -> LDS -> A-layout fragments
#pragma unroll
    for (int n = 0; n < 4; n++)
#pragma unroll
      for (int i = 0; i < 4; i++)
        myP[(lg * 4 + i) * 64 + n * 16 + l15] = f2bf(p[n][i]);
    asm volatile("s_waitcnt lgkmcnt(0)" ::: "memory");   // cross-lane via LDS
    s16x8 pa0 = *(const s16x8*)(myP + l15 * 64 + lg * 8);
    s16x8 pa1 = *(const s16x8*)(myP + l15 * 64 + 32 + lg * 8);
    asm volatile("s_waitcnt lgkmcnt(0)" ::: "memory");   // reads done before next overwrite

#pragma unroll
    for (int n = 0; n < 4; n++) {
      const short* vp = vb + (size_t)(n * 16 + l15) * S + kt + lg * 8;
      s16x8 v0 = *(const s16x8*)vp;
      s16x8 v1 = *(const s16x8*)(vp + 32);
      acc[n] = mfma_bf16(pa0, v0, acc[n]);
      acc[n] = mfma_bf16(pa1, v1, acc[n]);
    }
  }

  float inv[4];
#pragma unroll
  for (int i = 0; i < 4; i++) inv[i] = 1.f / lrow[i];
#pragma unroll
  for (int n = 0; n < 4; n++)
#pragma unroll
    for (int i = 0; i < 4; i++) {
      int qq = q0 + lg * 4 + i;
      int dc = n * 16 + l15;
      float v = acc[n][i] * inv[i];
      if (OUTMODE == 0)
        ((float*)outp)[((size_t)bh * S + qq) * DH + dc] = v;
      else
        ((short*)outp)[((size_t)(bh >> 4) * S + qq) * D + (bh & 15) * DH + dc] = f2bf(v);
    }
}

// ---------------- launch ----------------
extern "C" void kernel_launch(void* const* d_in, const int* in_sizes, int n_in,
                              void* d_out, int out_size, void* d_ws, size_t ws_size,
                              hipStream_t stream) {
  const float* xg = (const float*)d_in[0];
  const float* xl = (const float*)d_in[1];
  const float* xt = (const float*)d_in[2];
  const float* wf[7]; const float* bf_[7];
  for (int i = 0; i < 7; i++) { wf[i] = (const float*)d_in[3 + 2 * i]; bf_[i] = (const float*)d_in[4 + 2 * i]; }

  char* ws = (char*)d_ws;
  size_t off = 0;
  auto alloc = [&](size_t bytes) { void* p = ws + off; off += (bytes + 255) & ~(size_t)255; return p; };
  short* x16   = (short*)alloc((size_t)3 * M * KD * 2);   // xg16|xl16|xt16
  short* w16   = (short*)alloc((size_t)7 * KD * ND * 2);  // 7 weights
  short* gq16  = (short*)alloc((size_t)M * D * 2);
  short* gk16  = (short*)alloc((size_t)M * D * 2);
  float* gv32  = (float*)alloc((size_t)M * D * 4);
  short* pq16  = (short*)alloc((size_t)M * D * 2);
  short* pk16  = (short*)alloc((size_t)M * D * 2);
  short* pv16  = (short*)alloc((size_t)M * D * 2);
  short* pvt16 = (short*)alloc((size_t)M * D * 2);
  float* plb32 = (float*)alloc((size_t)M * D * 4);
  short* vpt16 = (short*)alloc((size_t)M * D * 2);
  short* last16= (short*)alloc((size_t)M * D * 2);
  (void)ws_size; (void)in_sizes; (void)n_in; (void)out_size;

  short* xg16 = x16;
  short* xl16 = x16 + (size_t)M * KD;
  short* xt16 = x16 + (size_t)2 * M * KD;

  Ptrs3 p3{xg, xl, xt};
  cast_inputs<<<3 * 4096, 256, 0, stream>>>(p3, x16);
  Ptrs7 p7; for (int i = 0; i < 7; i++) p7.p[i] = wf[i];
  cast_weights<<<7 * 1024, 256, 0, stream>>>(p7, w16);

  dim3 gg(ND / 128, M / 128);   // (8, 32)
  gemm_bt<0><<<gg, 256, 0, stream>>>(xg16, w16 + (size_t)0 * 1048576, bf_[0], gq16);
  gemm_bt<0><<<gg, 256, 0, stream>>>(xl16, w16 + (size_t)1 * 1048576, bf_[1], gk16);
  gemm_bt<1><<<gg, 256, 0, stream>>>(xl16, w16 + (size_t)2 * 1048576, bf_[2], gv32);
  gemm_bt<0><<<gg, 256, 0, stream>>>(xl16, w16 + (size_t)3 * 1048576, bf_[3], pq16);
  gemm_bt<0><<<gg, 256, 0, stream>>>(xt16, w16 + (size_t)4 * 1048576, bf_[4], pk16);
  gemm_bt<0><<<gg, 256, 0, stream>>>(xt16, w16 + (size_t)5 * 1048576, bf_[5], pv16);

  dim3 gt(S / 64, NB * NH);     // (16, 64)
  transpose_bf16<<<gt, 256, 0, stream>>>(pv16, pvt16);
  attn64<0><<<gt, 256, 0, stream>>>(pq16, pk16, pvt16, plb32);     // plb_attn
  vprime_t<<<gt, 256, 0, stream>>>(gv32, plb32, vpt16);            // v' = gv + plb_attn
  attn64<1><<<gt, 256, 0, stream>>>(gq16, gk16, vpt16, last16);    // last (merged, bf16)
  gemm_bt<2><<<gg, 256, 0, stream>>>(last16, w16 + (size_t)6 * 1048576, bf_[6], d_out);
}